// Round 8
// baseline (378.718 us; speedup 1.0000x reference)
//
#include <hip/hip_runtime.h>
#include <cstdint>
#include <cstddef>

// ---------------------------------------------------------------------------
// SeparableCritic: out = l2norm(MLP(x)) @ l2norm(MLP(y))^T
// N=8192, D=64, H=512, L=128. fp32 I/O, bf16 MFMA internals.
// Round 10: decisive fixed-floor test. R0/R4/R9 all ~375-381 despite three
// structural rewrites (predicted -40..-70 each); R8's +57 regression showed
// faithfully. Model says kernels ~90-130 us; profile top-5 = 1 GiB harness
// re-poison fills @ ~170 us. This round: every remaining safe kernel-side
// cut in one package:
//   * gemm1_direct: reads x/y fp32 directly (in-reg cast), LDS-free,
//     barrier-free, swapped-operand pattern copied from verified
//     gemm3_l2norm. Kills cast kernel + xy buffer. 5 -> 4+1 launches.
//   * gemm_nt: bijective XCD swizzle on block ids (nwg=4096 % 8 == 0).
//   * gemm2 / gemm3_l2norm / transpose_weights byte-identical controls.
// If still ~375: fixed harness floor confirmed -> ROOFLINE next round.
// ---------------------------------------------------------------------------

typedef unsigned short u16;
typedef __attribute__((ext_vector_type(8))) short bf16x8;  // 8 bf16 = 4 VGPRs
typedef __attribute__((ext_vector_type(4))) float f32x4;   // MFMA C/D
typedef __attribute__((ext_vector_type(4))) u16  u16x4;    // packed bf16 x4

__device__ __forceinline__ u16 f_to_bf16_bits(float f) {
    union { float f; uint32_t u; } v; v.f = f;
    uint32_t lsb = (v.u >> 16) & 1u;
    return (u16)((v.u + 0x7fffu + lsb) >> 16);   // round-to-nearest-even
}

// All three weight transpose+casts in one launch (range-dispatched).
// W1[64][512]->W1T[512][64]; W2[512][512]->W2T; W3[512][128]->W3T[128][512].
__global__ __launch_bounds__(256) void transpose_weights_kernel(
    const float* __restrict__ W1, const float* __restrict__ W2,
    const float* __restrict__ W3,
    u16* __restrict__ W1T, u16* __restrict__ W2T, u16* __restrict__ W3T)
{
    int idx = blockIdx.x * 256 + threadIdx.x;   // < 360448
    if (idx < 32768) {                           // W1: R=64, C=512
        int r = idx >> 9, c = idx & 511;
        W1T[c * 64 + r] = f_to_bf16_bits(W1[idx]);
    } else if (idx < 294912) {                   // W2: R=512, C=512
        int k = idx - 32768;
        int r = k >> 9, c = k & 511;
        W2T[c * 512 + r] = f_to_bf16_bits(W2[k]);
    } else if (idx < 360448) {                   // W3: R=512, C=128
        int k = idx - 294912;
        int r = k >> 7, c = k & 127;
        W3T[c * 512 + r] = f_to_bf16_bits(W3[k]);
    }
}

// Layer 1, direct: h1[row] = relu(in[row] @ W1 + b1). LDS-free, barrier-free.
// in = x rows 0..8191 / y rows 8192..16383, read fp32 + cast in-register
// (removes the standalone cast kernel and the xy bf16 buffer).
// Wave owns 16 rows (mi) x 256 cols (wch half); swapped MFMA operands
// (A-op = W1T col frag, B-op = input row frag): lane(mi,quad) reg r =
// h1[grow][cb*16 + quad*4 + r] -> u16x4 stores. Grid 512 x 256thr.
__global__ __launch_bounds__(256) void gemm1_direct_kernel(
    const float* __restrict__ X, const float* __restrict__ Y,
    const u16* __restrict__ W1T, const float* __restrict__ b1,
    u16* __restrict__ H1)
{
    const int lane = threadIdx.x & 63;
    const int wave = threadIdx.x >> 6;
    const int mi   = lane & 15;
    const int quad = lane >> 4;
    const int wrh  = wave >> 1;              // row half of block (0..1)
    const int wch  = wave & 1;               // col half (0..1)
    const int grow = blockIdx.x * 32 + wrh * 16 + mi;    // 0..16383
    const float* srow = (grow < 8192) ? (X + (size_t)grow * 64)
                                      : (Y + (size_t)(grow - 8192) * 64);

    // 16 fp32 -> 2 bf16x8 k-frags (k = ks*32 + quad*8 .. +7)
    bf16x8 xf[2];
    #pragma unroll
    for (int ks = 0; ks < 2; ++ks) {
        const float* p = srow + ks * 32 + quad * 8;
        float4 f0 = *reinterpret_cast<const float4*>(p);
        float4 f1 = *reinterpret_cast<const float4*>(p + 4);
        union { u16 u[8]; bf16x8 v; } cv;
        cv.u[0] = f_to_bf16_bits(f0.x); cv.u[1] = f_to_bf16_bits(f0.y);
        cv.u[2] = f_to_bf16_bits(f0.z); cv.u[3] = f_to_bf16_bits(f0.w);
        cv.u[4] = f_to_bf16_bits(f1.x); cv.u[5] = f_to_bf16_bits(f1.y);
        cv.u[6] = f_to_bf16_bits(f1.z); cv.u[7] = f_to_bf16_bits(f1.w);
        xf[ks] = cv.v;
    }

    u16* hrow = H1 + (size_t)grow * 512;
    #pragma unroll 1
    for (int cbg = 0; cbg < 4; ++cbg) {      // 4 col-blocks of 16 per iter
        f32x4 a[4];
        #pragma unroll
        for (int j = 0; j < 4; ++j) a[j] = f32x4{0.f, 0.f, 0.f, 0.f};
        #pragma unroll
        for (int j = 0; j < 4; ++j) {
            const int cb = wch * 16 + cbg * 4 + j;
            #pragma unroll
            for (int ks = 0; ks < 2; ++ks) {
                bf16x8 wf = *reinterpret_cast<const bf16x8*>(
                    W1T + (size_t)(cb * 16 + mi) * 64 + ks * 32 + quad * 8);
                a[j] = __builtin_amdgcn_mfma_f32_16x16x32_bf16(wf, xf[ks], a[j], 0, 0, 0);
            }
        }
        #pragma unroll
        for (int j = 0; j < 4; ++j) {
            const int cb = wch * 16 + cbg * 4 + j;
            const float* bp = b1 + cb * 16 + quad * 4;
            u16x4 pk;
            #pragma unroll
            for (int r = 0; r < 4; ++r)
                pk[r] = f_to_bf16_bits(fmaxf(a[j][r] + bp[r], 0.f));
            *reinterpret_cast<u16x4*>(hrow + cb * 16 + quad * 4) = pk;
        }
    }
}

// Layer 2: C[M,N] = relu(A[M,K] @ BT[N,K]^T + bias). A,BT row-major bf16.
// Block: 256 thr = 4 waves (2x2), 128x128 tile, each wave 64x64 (4x4 MFMA).
// m97-style global_load_lds staging into fragment-ordered LDS. (R4-verified.)
__global__ __launch_bounds__(256) void gemm_lds_kernel(
    const u16* __restrict__ A, const u16* __restrict__ BT,
    const float* __restrict__ bias,
    u16* __restrict__ Cb,
    int M, int N, int K)
{
    __shared__ u16 lds[16 * 512];   // 16 KB
    const int lane = threadIdx.x & 63;
    const int wave = threadIdx.x >> 6;
    const int wm = wave >> 1, wn = wave & 1;
    const int m_base = blockIdx.y * 128;
    const int n_base = blockIdx.x * 128;
    const int mi   = lane & 15;   // frag row / C col within 16-tile
    const int quad = lane >> 4;   // frag k-subrange; C row group

    f32x4 acc[4][4];
    #pragma unroll
    for (int i = 0; i < 4; ++i)
        #pragma unroll
        for (int j = 0; j < 4; ++j)
            acc[i][j] = f32x4{0.f, 0.f, 0.f, 0.f};

    const u16* src[4];
    #pragma unroll
    for (int s = 0; s < 4; ++s) {
        const int t = wave * 4 + s;
        if (t < 8)
            src[s] = A + (size_t)(m_base + t * 16 + mi) * K + quad * 8;
        else
            src[s] = BT + (size_t)(n_base + (t - 8) * 16 + mi) * K + quad * 8;
    }
    u16* dst_base = &lds[wave * 4 * 512];   // wave-uniform

    for (int k0 = 0; k0 < K; k0 += 32) {
        #pragma unroll
        for (int s = 0; s < 4; ++s) {
            __builtin_amdgcn_global_load_lds(
                (const __attribute__((address_space(1))) void*)(src[s] + k0),
                (__attribute__((address_space(3))) void*)(dst_base + s * 512),
                16, 0, 0);
        }
        __syncthreads();

        bf16x8 af[4], bfr[4];
        #pragma unroll
        for (int i = 0; i < 4; ++i)
            af[i] = *reinterpret_cast<const bf16x8*>(&lds[(wm * 4 + i) * 512 + lane * 8]);
        #pragma unroll
        for (int j = 0; j < 4; ++j)
            bfr[j] = *reinterpret_cast<const bf16x8*>(&lds[(8 + wn * 4 + j) * 512 + lane * 8]);

        #pragma unroll
        for (int i = 0; i < 4; ++i)
            #pragma unroll
            for (int j = 0; j < 4; ++j)
                acc[i][j] = __builtin_amdgcn_mfma_f32_16x16x32_bf16(
                    af[i], bfr[j], acc[i][j], 0, 0, 0);

        __syncthreads();
    }

    // Epilogue: C/D layout col = lane&15, row = quad*4 + reg [m89-verified].
    const int wm_base = m_base + wm * 64;
    const int wn_base = n_base + wn * 64;
    #pragma unroll
    for (int j = 0; j < 4; ++j) {
        const int col = wn_base + j * 16 + mi;
        float bv = bias[col];
        #pragma unroll
        for (int i = 0; i < 4; ++i) {
            const int row0 = wm_base + i * 16 + quad * 4;
            #pragma unroll
            for (int r = 0; r < 4; ++r) {
                float v = fmaxf(acc[i][j][r] + bv, 0.f);
                Cb[(size_t)(row0 + r) * N + col] = f_to_bf16_bits(v);
            }
        }
    }
}

// Fused GEMM3 + bias + L2-normalize (R9-verified):
//   zn[row] = l2norm(h2[row] @ W3 + b3), h2:[16384][512], W3T:[128][512].
// Wave owns 16 rows; swapped operands; sumsq via shfl_xor(16,32).
// Grid 256 x 256thr = full GPU. No barriers.
__global__ __launch_bounds__(256) void gemm3_l2norm_kernel(
    const u16* __restrict__ H2, const u16* __restrict__ W3T,
    const float* __restrict__ b3, u16* __restrict__ ZN)
{
    const int lane = threadIdx.x & 63;
    const int wave = threadIdx.x >> 6;
    const int mi   = lane & 15;
    const int quad = lane >> 4;
    const int grow = blockIdx.x * 64 + wave * 16 + mi;   // 0..16383

    bf16x8 hf[16];
    const u16* hbase = H2 + (size_t)grow * 512 + quad * 8;
    #pragma unroll
    for (int ks = 0; ks < 16; ++ks)
        hf[ks] = *reinterpret_cast<const bf16x8*>(hbase + ks * 32);

    f32x4 zv[8];
    #pragma unroll
    for (int cb = 0; cb < 8; ++cb) zv[cb] = f32x4{0.f, 0.f, 0.f, 0.f};

    const u16* wbase = W3T + (size_t)mi * 512 + quad * 8;
    #pragma unroll 1
    for (int ks = 0; ks < 16; ++ks) {
        #pragma unroll
        for (int cb = 0; cb < 8; ++cb) {
            bf16x8 wf = *reinterpret_cast<const bf16x8*>(
                wbase + (size_t)cb * 16 * 512 + ks * 32);
            zv[cb] = __builtin_amdgcn_mfma_f32_16x16x32_bf16(wf, hf[ks], zv[cb], 0, 0, 0);
        }
    }

    float s = 0.f;
    #pragma unroll
    for (int cb = 0; cb < 8; ++cb) {
        const float* bp = b3 + cb * 16 + quad * 4;
        #pragma unroll
        for (int r = 0; r < 4; ++r) {
            zv[cb][r] += bp[r];
            s += zv[cb][r] * zv[cb][r];
        }
    }
    s += __shfl_xor(s, 16, 64);
    s += __shfl_xor(s, 32, 64);
    const float inv = 1.0f / fmaxf(sqrtf(s), 1e-12f);

    u16* zrow = ZN + (size_t)grow * 128;
    #pragma unroll
    for (int cb = 0; cb < 8; ++cb) {
        u16x4 pk;
        #pragma unroll
        for (int r = 0; r < 4; ++r) pk[r] = f_to_bf16_bits(zv[cb][r] * inv);
        *reinterpret_cast<u16x4*>(zrow + cb * 16 + quad * 4) = pk;
    }
}

// Final GEMM: out[r][c] = znx[r] . zny[c], K=128, fp32 out. Barrier-free,
// LDS-free (R4-verified) + bijective XCD swizzle on block ids (nwg=4096,
// nwg%8==0): consecutive tiles share an XCD's L2 for zn reads / out writes.
__global__ __launch_bounds__(256) void gemm_nt_k128_kernel(
    const u16* __restrict__ ZX, const u16* __restrict__ ZY,
    float* __restrict__ out)
{
    const int lane = threadIdx.x & 63;
    const int wave = threadIdx.x >> 6;
    const int mi   = lane & 15;
    const int quad = lane >> 4;
    const int wr = wave >> 1, wc = wave & 1;

    // XCD swizzle: orig -> (orig%8)*512 + orig/8  (bijective, 4096 = 8*512)
    const int orig = blockIdx.y * 64 + blockIdx.x;
    const int swz  = (orig & 7) * 512 + (orig >> 3);
    const int rb = (swz >> 6) * 128 + wr * 64;   // out rows (znx)
    const int cb = (swz & 63) * 128 + wc * 64;   // out cols (zny)

    f32x4 acc[4][4];   // [ci][rj]
    #pragma unroll
    for (int ci = 0; ci < 4; ++ci)
        #pragma unroll
        for (int rj = 0; rj < 4; ++rj)
            acc[ci][rj] = f32x4{0.f, 0.f, 0.f, 0.f};

    const u16* xbase = ZX + (size_t)(rb + mi) * 128 + quad * 8;
    const u16* ybase = ZY + (size_t)(cb + mi) * 128 + quad * 8;

    #pragma unroll
    for (int ks = 0; ks < 4; ++ks) {
        bf16x8 yf[4], xf[4];
        #pragma unroll
        for (int t = 0; t < 4; ++t) {
            yf[t] = *reinterpret_cast<const bf16x8*>(ybase + (size_t)t * 16 * 128 + ks * 32);
            xf[t] = *reinterpret_cast<const bf16x8*>(xbase + (size_t)t * 16 * 128 + ks * 32);
        }
        #pragma unroll
        for (int ci = 0; ci < 4; ++ci)
            #pragma unroll
            for (int rj = 0; rj < 4; ++rj)
                acc[ci][rj] = __builtin_amdgcn_mfma_f32_16x16x32_bf16(
                    yf[ci], xf[rj], acc[ci][rj], 0, 0, 0);
    }

    #pragma unroll
    for (int rj = 0; rj < 4; ++rj) {
        float* orow = out + (size_t)(rb + rj * 16 + mi) * 8192 + cb + quad * 4;
        #pragma unroll
        for (int ci = 0; ci < 4; ++ci)
            *reinterpret_cast<f32x4*>(orow + ci * 16) = acc[ci][rj];
    }
}

extern "C" void kernel_launch(void* const* d_in, const int* in_sizes, int n_in,
                              void* d_out, int out_size, void* d_ws, size_t ws_size,
                              hipStream_t stream)
{
    const float* x  = (const float*)d_in[0];   // [8192, 64]
    const float* y  = (const float*)d_in[1];   // [8192, 64]
    const float* W1 = (const float*)d_in[2];   // [64, 512]
    const float* b1 = (const float*)d_in[3];   // [512]
    const float* W2 = (const float*)d_in[4];   // [512, 512]
    const float* b2 = (const float*)d_in[5];   // [512]
    const float* W3 = (const float*)d_in[6];   // [512, 128]
    const float* b3 = (const float*)d_in[7];   // [128]
    float* out = (float*)d_out;                // [8192, 8192] fp32

    // Workspace (all bf16 as u16). ~38 MB.
    u16* ws  = (u16*)d_ws;
    u16* W1T = ws;                              // [512][64]
    u16* W2T = W1T + 512 * 64;                  // [512][512]
    u16* W3T = W2T + 512 * 512;                 // [128][512]
    u16* h1  = W3T + 128 * 512;                 // [16384][512]
    u16* h2  = h1  + (size_t)16384 * 512;       // [16384][512]
    u16* zn  = h2  + (size_t)16384 * 512;       // [16384][128]

    dim3 blk(256);

    // 1. All weight transposes, one launch (360448 elems).
    transpose_weights_kernel<<<1408, blk, 0, stream>>>(
        W1, W2, W3, W1T, W2T, W3T);

    // 2. Layer 1 direct from fp32 x/y (no cast kernel, no xy buffer).
    gemm1_direct_kernel<<<512, blk, 0, stream>>>(x, y, W1T, b1, h1);

    // 3. Layer 2 (LDS template, M=16384, N=512, K=512).
    gemm_lds_kernel<<<dim3(4, 128), blk, 0, stream>>>(
        h1, W2T, b2, h2, 16384, 512, 512);

    // 4. Layer 3 + bias + l2norm, full GPU.
    gemm3_l2norm_kernel<<<256, blk, 0, stream>>>(h2, W3T, b3, zn);

    // 5. out = zx @ zy^T (TEMP=1.0), XCD-swizzled.
    gemm_nt_k128_kernel<<<dim3(64, 64), blk, 0, stream>>>(
        zn, zn + (size_t)8192 * 128, out);
}